// Round 9
// baseline (133.013 us; speedup 1.0000x reference)
//
#include <hip/hip_runtime.h>
#include <stdint.h>

// Problem constants (fixed by reference)
#define BATCH 16
#define CH    512
#define HW    2304           // 48*48
#define BM    128
#define BN    128
#define BK    32             // f32 K-elems per step
#define NKT   (HW / BK)      // 72 K-steps

typedef _Float16 half8  __attribute__((ext_vector_type(8)));
typedef float    f32x16 __attribute__((ext_vector_type(16)));

#define TILE_A 16384         // 128 rows x 128 B (f32 K32 slice)
#define BUF_SZ 32768         // A tile + B tile
// 3 rotating buffers = 96 KB (1 block/CU). m201 template proves >64KB static
// LDS works in plain HIP on gfx950.

#define MFMA16 __builtin_amdgcn_mfma_f32_32x32x16_f16

// float -> order-preserving uint32
__device__ __forceinline__ uint32_t f32_sortable(float f) {
    uint32_t u = __float_as_uint(f);
    return (u & 0x80000000u) ? ~u : (u | 0x80000000u);
}

// f32 tile [128 rows][8 slots x 16B], row pitch 128 B. DMA writes are linear
// (HW constraint m104), so the swizzle lives in the per-lane GLOBAL source
// address (m173): LDS[r][s] holds G[r][s ^ (r&7)]. Read of G[r][s0] uses slot
// s0^(r&7): within a 16-lane phase (16 consecutive rows) every slot value
// appears exactly twice -> 2 words/bank = conflict-free floor. DMA writes:
// lane*16 contiguous -> conflict-free.
__device__ __forceinline__ int swzf32(int r, int s) {
    return r * 128 + ((s ^ (r & 7)) << 4);
}

__device__ __forceinline__ void dma16(const float* g, char* l) {
    __builtin_amdgcn_global_load_lds(
        (const __attribute__((address_space(1))) void*)g,
        (__attribute__((address_space(3))) void*)l, 16, 0, 0);
}

// Stage one K32 tile (A rows 16w..16w+15, B rows 16w..16w+15) via 4 DMA instrs.
// Per-lane source offset (folded into gA/gB): row lane>>3, slot (lane&7)^(lane>>3).
__device__ __forceinline__ void dma_step(char* lb, const float* gA0, const float* gA1,
                                         const float* gB0, const float* gB1,
                                         int ko, int w2) {
    dma16(gA0 + ko, lb + w2 * 1024);
    dma16(gA1 + ko, lb + w2 * 1024 + 1024);
    dma16(gB0 + ko, lb + TILE_A + w2 * 1024);
    dma16(gB1 + ko, lb + TILE_A + w2 * 1024 + 1024);
}

// Read one fragment (8 consecutive K f32 of row r starting at slot s0) and
// split to f16 hi/lo in registers. All indices static after unroll (rule #20).
__device__ __forceinline__ void rdfrag(const char* base, int r, int s0,
                                       half8& h, half8& l) {
    float4 v0 = *(const float4*)(base + swzf32(r, s0));
    float4 v1 = *(const float4*)(base + swzf32(r, s0 + 1));
    float vv[8] = {v0.x, v0.y, v0.z, v0.w, v1.x, v1.y, v1.z, v1.w};
    #pragma unroll
    for (int j = 0; j < 8; ++j) {
        _Float16 hh = (_Float16)vv[j];
        h[j] = hh;
        l[j] = (_Float16)(vv[j] - (float)hh);
    }
}

// One K16 (this wave's kc half) of a 64x64 wave tile: 8 ds_read_b128 -> 12 MFMA.
__device__ __forceinline__ void compute_step(const char* buf, int rA0, int rB0, int s0,
                                             f32x16& a00, f32x16& a01,
                                             f32x16& a10, f32x16& a11) {
    const char* bA = buf;
    const char* bB = buf + TILE_A;
    half8 ah0, al0, ah1, al1, bh0, bl0, bh1, bl1;
    rdfrag(bA, rA0,      s0, ah0, al0);
    rdfrag(bA, rA0 + 32, s0, ah1, al1);
    rdfrag(bB, rB0,      s0, bh0, bl0);
    rdfrag(bB, rB0 + 32, s0, bh1, bl1);
    a00 = MFMA16(ah0, bh0, a00, 0, 0, 0);
    a01 = MFMA16(ah0, bh1, a01, 0, 0, 0);
    a10 = MFMA16(ah1, bh0, a10, 0, 0, 0);
    a11 = MFMA16(ah1, bh1, a11, 0, 0, 0);
    a00 = MFMA16(ah0, bl0, a00, 0, 0, 0);
    a01 = MFMA16(ah0, bl1, a01, 0, 0, 0);
    a10 = MFMA16(ah1, bl0, a10, 0, 0, 0);
    a11 = MFMA16(ah1, bl1, a11, 0, 0, 0);
    a00 = MFMA16(al0, bh0, a00, 0, 0, 0);
    a01 = MFMA16(al0, bh1, a01, 0, 0, 0);
    a10 = MFMA16(al1, bh0, a10, 0, 0, 0);
    a11 = MFMA16(al1, bh1, a11, 0, 0, 0);
}

// merge-slot helpers (2-way max conflicts; one-time cost)
#define STACC(A, aidx) { \
    char* bp = sm + (p * 4 + (aidx)) * 4096 + lane * 64; \
    *(float4*)(bp + ((0 ^ (lane & 3)) << 4)) = make_float4(A[0], A[1], A[2], A[3]); \
    *(float4*)(bp + ((1 ^ (lane & 3)) << 4)) = make_float4(A[4], A[5], A[6], A[7]); \
    *(float4*)(bp + ((2 ^ (lane & 3)) << 4)) = make_float4(A[8], A[9], A[10], A[11]); \
    *(float4*)(bp + ((3 ^ (lane & 3)) << 4)) = make_float4(A[12], A[13], A[14], A[15]); }

#define LDACC(A, aidx) { \
    const char* bp = sm + (p * 4 + (aidx)) * 4096 + lane * 64; \
    float4 v; \
    v = *(const float4*)(bp + ((0 ^ (lane & 3)) << 4)); A[0]+=v.x; A[1]+=v.y; A[2]+=v.z; A[3]+=v.w; \
    v = *(const float4*)(bp + ((1 ^ (lane & 3)) << 4)); A[4]+=v.x; A[5]+=v.y; A[6]+=v.z; A[7]+=v.w; \
    v = *(const float4*)(bp + ((2 ^ (lane & 3)) << 4)); A[8]+=v.x; A[9]+=v.y; A[10]+=v.z; A[11]+=v.w; \
    v = *(const float4*)(bp + ((3 ^ (lane & 3)) << 4)); A[12]+=v.x; A[13]+=v.y; A[14]+=v.z; A[15]+=v.w; }

// K1: energy = Q.K^T per batch, split-f16 MFMA (hh+hl+lh), DMA staging with
// counted vmcnt + raw barriers (T3/T4), kc-split wave pairs (w, w+4) sharing a
// 64x64 tile (each owns one K16 half per step), LDS acc-merge, fused argmax.
__global__ __launch_bounds__(512, 2)
void energy_argmax_kernel(const float* __restrict__ q,    // rgb   [B][C][HW]
                          const float* __restrict__ kmat, // depth [B][C][HW]
                          unsigned long long* __restrict__ best) // [B][C]
{
    const int bid = blockIdx.x;
    const int nid = (bid & 7) * 32 + (bid >> 3);   // XCD-chunk (256%8==0: bijective)
    const int d0  = (nid & 3) * BN;
    const int c0  = ((nid >> 2) & 3) * BM;
    const int b   = nid >> 4;

    const int tid  = threadIdx.x;
    const int lane = tid & 63;
    const int w    = tid >> 6;     // 0..7
    const int kc   = w >> 2;       // K16 half owned by this wave
    const int p    = w & 3;        // tile position; waves p and p+4 share a tile
    const int wm   = p >> 1, wn = p & 1;
    const int w2   = 2 * w;

    __shared__ __align__(16) char sm[3 * BUF_SZ];

    const float* qb = q    + (size_t)b * CH * HW;
    const float* kb = kmat + (size_t)b * CH * HW;

    // per-lane DMA source offset (f32 units): row lane>>3, slot (lane&7)^(lane>>3)
    const int dml = (lane >> 3) * HW + (((lane & 7) ^ (lane >> 3)) << 2);
    const float* gA0 = qb + (size_t)(c0 + 16 * w)     * HW + dml;
    const float* gA1 = qb + (size_t)(c0 + 16 * w + 8) * HW + dml;
    const float* gB0 = kb + (size_t)(d0 + 16 * w)     * HW + dml;
    const float* gB1 = kb + (size_t)(d0 + 16 * w + 8) * HW + dml;

    // ---- prologue: tiles 0,1 in flight; wait tile 0 (own oldest 4) ----
    dma_step(sm,          gA0, gA1, gB0, gB1, 0,  w2);
    dma_step(sm + BUF_SZ, gA0, gA1, gB0, gB1, BK, w2);
    asm volatile("s_waitcnt vmcnt(4)" ::: "memory");
    __builtin_amdgcn_s_barrier();
    __builtin_amdgcn_sched_barrier(0);

    f32x16 a00 = {}, a01 = {}, a10 = {}, a11 = {};
    const int rA0 = wm * 64 + (lane & 31);
    const int rB0 = wn * 64 + (lane & 31);
    const int s0  = 4 * kc + 2 * (lane >> 5);   // f32 slot of this frag's K8

    for (int t = 0; t < NKT - 2; ++t) {
        // stage t+2 (its buffer's tile-(t-1) reads finished before last barrier)
        dma_step(sm + ((t + 2) % 3) * BUF_SZ, gA0, gA1, gB0, gB1, (t + 2) * BK, w2);
        compute_step(sm + (t % 3) * BUF_SZ, rA0, rB0, s0, a00, a01, a10, a11);
        // own outstanding: t+1 (4, oldest) + t+2 (4) -> vmcnt(4) = t+1 landed
        asm volatile("s_waitcnt vmcnt(4)" ::: "memory");
        __builtin_amdgcn_s_barrier();
        __builtin_amdgcn_sched_barrier(0);
    }
    compute_step(sm + ((NKT - 2) % 3) * BUF_SZ, rA0, rB0, s0, a00, a01, a10, a11);
    asm volatile("s_waitcnt vmcnt(0)" ::: "memory");
    __builtin_amdgcn_s_barrier();
    __builtin_amdgcn_sched_barrier(0);
    compute_step(sm + ((NKT - 1) % 3) * BUF_SZ, rA0, rB0, s0, a00, a01, a10, a11);

    // ---- kc-split merge: waves 4-7 write accs into bytes 0..64K (last-read
    // tile buffer is (NKT-1)%3 == 2 at 64K..96K -> disjoint), waves 0-3 add ----
    if (w >= 4) { STACC(a00, 0) STACC(a01, 1) STACC(a10, 2) STACC(a11, 3) }
    __syncthreads();
    if (w < 4) {
        LDACC(a00, 0) LDACC(a01, 1) LDACC(a10, 2) LDACC(a11, 3)

        // ---- argmax epilogue over this wave's 64x64 tile ----
        // C/D map (m74/m101): col = lane&31, row = (reg&3)+8*(reg>>2)+4*(lane>>5)
        const uint32_t didx0 = ~(uint32_t)(d0 + wn * 64 +      (lane & 31));
        const uint32_t didx1 = ~(uint32_t)(d0 + wn * 64 + 32 + (lane & 31));
        #pragma unroll
        for (int mi = 0; mi < 2; ++mi) {
            #pragma unroll
            for (int qr = 0; qr < 16; ++qr) {
                float v0 = (mi == 0) ? a00[qr] : a10[qr];
                float v1 = (mi == 0) ? a01[qr] : a11[qr];
                int rowl = wm * 64 + mi * 32 + (qr & 3) + 8 * (qr >> 2) + 4 * (lane >> 5);
                unsigned long long p0 =
                    ((unsigned long long)f32_sortable(v0) << 32) | didx0;
                unsigned long long p1 =
                    ((unsigned long long)f32_sortable(v1) << 32) | didx1;
                unsigned long long pk = p0 > p1 ? p0 : p1;
                #pragma unroll
                for (int off = 1; off < 32; off <<= 1) {
                    unsigned long long o = __shfl_xor(pk, off, 64);
                    if (o > pk) pk = o;
                }
                if ((lane & 31) == 0)
                    atomicMax(&best[(size_t)b * CH + c0 + rowl], pk);
            }
        }
    }
}

// K2: out[b][c][:] = rgb[b][c][:] + depth[b][argmax][:]
__global__ __launch_bounds__(256)
void gather_add_kernel(const float* __restrict__ rgb,
                       const float* __restrict__ depth,
                       const unsigned long long* __restrict__ best,
                       float* __restrict__ out)
{
    const int row = blockIdx.x;          // b*CH + c
    const int b   = row >> 9;            // /512
    const uint32_t idx = ~(uint32_t)(best[row] & 0xFFFFFFFFull);
    const float4* src = (const float4*)(rgb   + (size_t)row * HW);
    const float4* dep = (const float4*)(depth + ((size_t)b * CH + idx) * HW);
    float4*       dst = (float4*)(out + (size_t)row * HW);
    for (int j = threadIdx.x; j < HW / 4; j += 256) {
        float4 a = src[j], d = dep[j];
        float4 r; r.x = a.x + d.x; r.y = a.y + d.y; r.z = a.z + d.z; r.w = a.w + d.w;
        dst[j] = r;
    }
}

extern "C" void kernel_launch(void* const* d_in, const int* in_sizes, int n_in,
                              void* d_out, int out_size, void* d_ws, size_t ws_size,
                              hipStream_t stream)
{
    const float* rgb   = (const float*)d_in[0];
    const float* depth = (const float*)d_in[1];
    float* out = (float*)d_out;
    unsigned long long* best = (unsigned long long*)d_ws;  // 16*512*8 = 64 KB

    hipMemsetAsync(best, 0, (size_t)BATCH * CH * sizeof(unsigned long long), stream);

    energy_argmax_kernel<<<256, 512, 0, stream>>>(rgb, depth, best);

    gather_add_kernel<<<BATCH * CH, 256, 0, stream>>>(rgb, depth, best, out);
}

// Round 10
// 129.950 us; speedup vs baseline: 1.0236x; 1.0236x over previous
//
#include <hip/hip_runtime.h>
#include <stdint.h>

// Problem constants (fixed by reference)
#define BATCH 16
#define CH    512
#define HW    2304           // 48*48
#define BM    64
#define BN    128
#define BK    32
#define NKT   (HW / BK)      // 72 K-steps

typedef _Float16 half8  __attribute__((ext_vector_type(8)));
typedef float    f32x16 __attribute__((ext_vector_type(16)));

// LDS per buffer: A-hi | A-lo (64 rows x 64B) | B-hi | B-lo (128 rows x 64B)
#define AH_OFF 0
#define AL_OFF 4096
#define BH_OFF 8192
#define BL_OFF 16384
#define BUF_SZ 24576         // 24 KB ; x2 buffers = 48 KB/block ; 2 blocks/CU = 96 KB

#define MFMA16 __builtin_amdgcn_mfma_f32_32x32x16_f16

// lgkm-only barrier: ds traffic must drain (cross-wave visibility), but the
// outstanding t+2 global loads target private VGPRs -> legally span the
// barrier (T4). __syncthreads would drain vmcnt(0) = the m97 ~20% stall.
#define LGKM_BARRIER() do { \
    asm volatile("s_waitcnt lgkmcnt(0)" ::: "memory"); \
    __builtin_amdgcn_s_barrier(); \
    __builtin_amdgcn_sched_barrier(0); \
} while (0)

// float -> order-preserving uint32
__device__ __forceinline__ uint32_t f32_sortable(float f) {
    uint32_t u = __float_as_uint(f);
    return (u & 0x80000000u) ? ~u : (u | 0x80000000u);
}

// [rows][32 f16] tile, pitch 64B, 4x16B slots; slot ^= (r>>1)&3 (R8-verified:
// balanced per 16-lane phase for reads; re-derived balanced for this round's
// A-writes {q} and B-writes {2h,2h+1} patterns; row-local -> bijective).
__device__ __forceinline__ int swz(int r, int cb) {
    return r * 64 + (cb ^ (((r >> 1) & 3) << 4));
}

__device__ __forceinline__ void cvt8(const float4& v0, const float4& v1,
                                     half8& h, half8& l) {
    float vv[8] = {v0.x, v0.y, v0.z, v0.w, v1.x, v1.y, v1.z, v1.w};
    #pragma unroll
    for (int j = 0; j < 8; ++j) {
        _Float16 hh = (_Float16)vv[j];
        h[j] = hh;
        l[j] = (_Float16)(vv[j] - (float)hh);
    }
}

// Staging (256 thr): A: 4 thr/row (row=tid>>2, q=tid&3, 8 f32);
//                    B: 2 thr/row (row=tid>>1, h=tid&1, 16 f32).
// aG pre-offset by q*8, bG by h*16. Static indices only (rule #20).
__device__ __forceinline__ void load_tile(const float* aG, const float* bG, int k0,
                                          float4 (&av)[2], float4 (&bv)[4]) {
    av[0] = *(const float4*)(aG + k0 + 0);
    av[1] = *(const float4*)(aG + k0 + 4);
    bv[0] = *(const float4*)(bG + k0 + 0);
    bv[1] = *(const float4*)(bG + k0 + 4);
    bv[2] = *(const float4*)(bG + k0 + 8);
    bv[3] = *(const float4*)(bG + k0 + 12);
}

// Write-side cvt (once per element, off the MFMA critical path — R9 lesson).
__device__ __forceinline__ void stage_tile(char* dst,
                                           const float4 (&av)[2], const float4 (&bv)[4],
                                           int arow, int q, int brow, int h) {
    half8 hh, ll;
    cvt8(av[0], av[1], hh, ll);                    // A slot q
    *(half8*)(dst + AH_OFF + swz(arow, q * 16)) = hh;
    *(half8*)(dst + AL_OFF + swz(arow, q * 16)) = ll;
    cvt8(bv[0], bv[1], hh, ll);                    // B slot 2h
    *(half8*)(dst + BH_OFF + swz(brow, h * 32)) = hh;
    *(half8*)(dst + BL_OFF + swz(brow, h * 32)) = ll;
    cvt8(bv[2], bv[3], hh, ll);                    // B slot 2h+1
    *(half8*)(dst + BH_OFF + swz(brow, h * 32 + 16)) = hh;
    *(half8*)(dst + BL_OFF + swz(brow, h * 32 + 16)) = ll;
}

// One K32 step for a 64x32 wave tile: 12 ds_read_b128 -> 12 MFMA.
__device__ __forceinline__ void compute_tile(const char* buf, int rA0, int rB, int hb,
                                             f32x16& acc0, f32x16& acc1) {
    __builtin_amdgcn_s_setprio(1);
    #pragma unroll
    for (int kc = 0; kc < 2; ++kc) {
        const int cb = kc * 32 + hb;
        half8 ah0 = *(const half8*)(buf + AH_OFF + swz(rA0,      cb));
        half8 ah1 = *(const half8*)(buf + AH_OFF + swz(rA0 + 32, cb));
        half8 al0 = *(const half8*)(buf + AL_OFF + swz(rA0,      cb));
        half8 al1 = *(const half8*)(buf + AL_OFF + swz(rA0 + 32, cb));
        half8 bh  = *(const half8*)(buf + BH_OFF + swz(rB, cb));
        half8 bl  = *(const half8*)(buf + BL_OFF + swz(rB, cb));
        acc0 = MFMA16(ah0, bh, acc0, 0, 0, 0);
        acc1 = MFMA16(ah1, bh, acc1, 0, 0, 0);
        acc0 = MFMA16(ah0, bl, acc0, 0, 0, 0);
        acc1 = MFMA16(ah1, bl, acc1, 0, 0, 0);
        acc0 = MFMA16(al0, bh, acc0, 0, 0, 0);
        acc1 = MFMA16(al1, bh, acc1, 0, 0, 0);
    }
    __builtin_amdgcn_s_setprio(0);
}

// K1: energy = Q.K^T per batch via split-f16 MFMA (hh+hl+lh), fused argmax.
// 64x128 block tile, 4 waves of 64x32, 256 threads. Grid 512 = 2 blocks/CU:
// independent barrier domains break R8's convoy (1 block lockstep = 55% LDS
// idle). lgkm-only barriers let global prefetch span barriers.
__global__ __launch_bounds__(256, 2)
void energy_argmax_kernel(const float* __restrict__ q,    // rgb   [B][C][HW]
                          const float* __restrict__ kmat, // depth [B][C][HW]
                          unsigned long long* __restrict__ best) // [B][C]
{
    const int bid = blockIdx.x;
    const int nid = (bid & 7) * 64 + (bid >> 3);   // XCD-chunk (512%8==0: bijective)
    const int d0  = (nid & 3) * BN;
    const int c0  = ((nid >> 2) & 7) * BM;
    const int b   = nid >> 5;

    const int tid  = threadIdx.x;
    const int lane = tid & 63;
    const int w    = tid >> 6;     // 0..3, wave owns cols w*32..w*32+31

    __shared__ __align__(16) char sm[2 * BUF_SZ];
    char* buf0 = sm;
    char* buf1 = sm + BUF_SZ;

    const float* qb = q    + (size_t)b * CH * HW;
    const float* kb = kmat + (size_t)b * CH * HW;

    const int arow = tid >> 2, aq = tid & 3;
    const int brow = tid >> 1, bh = tid & 1;
    const float* aG = qb + (size_t)(c0 + arow) * HW + aq * 8;
    const float* bG = kb + (size_t)(d0 + brow) * HW + bh * 16;

    float4 av0[2], bv0[4], av1[2], bv1[4];

    // ---- prologue: tile0 -> buf0 ; tile1 loads in flight ----
    load_tile(aG, bG, 0, av0, bv0);
    stage_tile(buf0, av0, bv0, arow, aq, brow, bh);
    load_tile(aG, bG, BK, av1, bv1);
    LGKM_BARRIER();

    f32x16 acc0 = {}, acc1 = {};

    const int rA0 = lane & 31;
    const int rB  = w * 32 + (lane & 31);
    const int hb  = (lane >> 5) * 16;              // 16B half-select within K16

    for (int kt = 0; kt < NKT; kt += 2) {
        // phase A: compute tile kt (buf0); stage kt+1 -> buf1; load kt+2
        if (kt + 2 < NKT) load_tile(aG, bG, (kt + 2) * BK, av0, bv0);
        compute_tile(buf0, rA0, rB, hb, acc0, acc1);
        stage_tile(buf1, av1, bv1, arow, aq, brow, bh);
        LGKM_BARRIER();
        // phase B: compute tile kt+1 (buf1); stage kt+2 -> buf0; load kt+3
        if (kt + 3 < NKT) load_tile(aG, bG, (kt + 3) * BK, av1, bv1);
        compute_tile(buf1, rA0, rB, hb, acc0, acc1);
        if (kt + 2 < NKT) stage_tile(buf0, av0, bv0, arow, aq, brow, bh);
        LGKM_BARRIER();
    }

    // ---- epilogue: per-row argmax over this wave's 64x32 tile ----
    // C/D map (m74/m101): col = lane&31, row = (reg&3) + 8*(reg>>2) + 4*(lane>>5)
    const uint32_t didx = ~(uint32_t)(d0 + w * 32 + (lane & 31));  // ties -> smallest d
    #pragma unroll
    for (int mi = 0; mi < 2; ++mi) {
        #pragma unroll
        for (int qr = 0; qr < 16; ++qr) {
            float v = (mi == 0) ? acc0[qr] : acc1[qr];
            int rowl = mi * 32 + (qr & 3) + 8 * (qr >> 2) + 4 * (lane >> 5);
            unsigned long long p =
                ((unsigned long long)f32_sortable(v) << 32) | didx;
            #pragma unroll
            for (int off = 1; off < 32; off <<= 1) {   // reduce 32 cols (stays in half)
                unsigned long long o = __shfl_xor(p, off, 64);
                if (o > p) p = o;
            }
            if ((lane & 31) == 0)
                atomicMax(&best[(size_t)b * CH + c0 + rowl], p);
        }
    }
}

// K2: out[b][c][:] = rgb[b][c][:] + depth[b][argmax][:]
__global__ __launch_bounds__(256)
void gather_add_kernel(const float* __restrict__ rgb,
                       const float* __restrict__ depth,
                       const unsigned long long* __restrict__ best,
                       float* __restrict__ out)
{
    const int row = blockIdx.x;          // b*CH + c
    const int b   = row >> 9;            // /512
    const uint32_t idx = ~(uint32_t)(best[row] & 0xFFFFFFFFull);
    const float4* src = (const float4*)(rgb   + (size_t)row * HW);
    const float4* dep = (const float4*)(depth + ((size_t)b * CH + idx) * HW);
    float4*       dst = (float4*)(out + (size_t)row * HW);
    for (int j = threadIdx.x; j < HW / 4; j += 256) {
        float4 a = src[j], d = dep[j];
        float4 r; r.x = a.x + d.x; r.y = a.y + d.y; r.z = a.z + d.z; r.w = a.w + d.w;
        dst[j] = r;
    }
}

extern "C" void kernel_launch(void* const* d_in, const int* in_sizes, int n_in,
                              void* d_out, int out_size, void* d_ws, size_t ws_size,
                              hipStream_t stream)
{
    const float* rgb   = (const float*)d_in[0];
    const float* depth = (const float*)d_in[1];
    float* out = (float*)d_out;
    unsigned long long* best = (unsigned long long*)d_ws;  // 16*512*8 = 64 KB

    hipMemsetAsync(best, 0, (size_t)BATCH * CH * sizeof(unsigned long long), stream);

    energy_argmax_kernel<<<512, 256, 0, stream>>>(rgb, depth, best);

    gather_add_kernel<<<BATCH * CH, 256, 0, stream>>>(rgb, depth, best, out);
}

// Round 11
// 123.183 us; speedup vs baseline: 1.0798x; 1.0549x over previous
//
#include <hip/hip_runtime.h>
#include <stdint.h>

// Problem constants (fixed by reference)
#define BATCH 16
#define CH    512
#define HW    2304           // 48*48
#define BM    128
#define BN    128
#define BK    64             // f32 K-elems per step (R11: was 32 -> halves barriers)
#define NKT   (HW / BK)      // 36 K-steps

typedef _Float16 half8  __attribute__((ext_vector_type(8)));
typedef float    f32x16 __attribute__((ext_vector_type(16)));

// LDS per buffer: A-hi | A-lo | B-hi | B-lo, each 128 rows x 128 B
#define AH_OFF 0
#define AL_OFF 16384
#define BH_OFF 32768
#define BL_OFF 49152
#define BUF_SZ 65536         // 64 KB ; x2 buffers = 128 KB (1 block/CU; m201-proven)

#define MFMA16 __builtin_amdgcn_mfma_f32_32x32x16_f16

// lgkm-only barrier: ds traffic drains (cross-wave visibility); outstanding
// global prefetch loads target private VGPRs -> legally span the barrier.
#define LGKM_BARRIER() do { \
    asm volatile("s_waitcnt lgkmcnt(0)" ::: "memory"); \
    __builtin_amdgcn_s_barrier(); \
    __builtin_amdgcn_sched_barrier(0); \
} while (0)

// float -> order-preserving uint32
__device__ __forceinline__ uint32_t f32_sortable(float f) {
    uint32_t u = __float_as_uint(f);
    return (u & 0x80000000u) ? ~u : (u | 0x80000000u);
}

// [rows][64 f16] tile, pitch 128 B = exactly 32 banks, 8 x 16B slots.
// slot ^= (r>>1)&7 : over any 16 consecutive rows each slot value appears
// exactly twice -> 2 accesses/bank per 16-lane phase = b128 floor, for reads
// (fixed s0, rows=lane&31) AND writes (4 thr/row q=0..3, slots {2q,2q+1},
// f(r)={0,0,1,1} over the 4 rows of a phase -> all 8 slots x2). Row-local
// XOR -> bijective (R3 lesson).
__device__ __forceinline__ int swz(int r, int s) {
    return r * 128 + ((s ^ ((r >> 1) & 7)) << 4);
}

__device__ __forceinline__ void cvt8(const float4& v0, const float4& v1,
                                     half8& h, half8& l) {
    float vv[8] = {v0.x, v0.y, v0.z, v0.w, v1.x, v1.y, v1.z, v1.w};
    #pragma unroll
    for (int j = 0; j < 8; ++j) {
        _Float16 hh = (_Float16)vv[j];
        h[j] = hh;
        l[j] = (_Float16)(vv[j] - (float)hh);
    }
}

// Staging (512 thr): A and B each 128 rows x 64 f32; 4 thr/row (r=tid>>2,
// q=tid&3), each owns f32 [16q,16q+16) of its row. Static indices (rule #20).
__device__ __forceinline__ void load_tile(const float* aG, const float* bG, int k0,
                                          float4 (&av)[4], float4 (&bv)[4]) {
    av[0] = *(const float4*)(aG + k0 + 0);
    av[1] = *(const float4*)(aG + k0 + 4);
    av[2] = *(const float4*)(aG + k0 + 8);
    av[3] = *(const float4*)(aG + k0 + 12);
    bv[0] = *(const float4*)(bG + k0 + 0);
    bv[1] = *(const float4*)(bG + k0 + 4);
    bv[2] = *(const float4*)(bG + k0 + 8);
    bv[3] = *(const float4*)(bG + k0 + 12);
}

// Write-side cvt (R9 lesson: once per element, off the MFMA critical path).
// 8 b128 writes/thread: A slots 2q,2q+1 (hi+lo), B same.
__device__ __forceinline__ void stage_tile(char* dst,
                                           const float4 (&av)[4], const float4 (&bv)[4],
                                           int row, int q) {
    half8 h, l;
    cvt8(av[0], av[1], h, l);
    *(half8*)(dst + AH_OFF + swz(row, 2 * q))     = h;
    *(half8*)(dst + AL_OFF + swz(row, 2 * q))     = l;
    cvt8(av[2], av[3], h, l);
    *(half8*)(dst + AH_OFF + swz(row, 2 * q + 1)) = h;
    *(half8*)(dst + AL_OFF + swz(row, 2 * q + 1)) = l;
    cvt8(bv[0], bv[1], h, l);
    *(half8*)(dst + BH_OFF + swz(row, 2 * q))     = h;
    *(half8*)(dst + BL_OFF + swz(row, 2 * q))     = l;
    cvt8(bv[2], bv[3], h, l);
    *(half8*)(dst + BH_OFF + swz(row, 2 * q + 1)) = h;
    *(half8*)(dst + BL_OFF + swz(row, 2 * q + 1)) = l;
}

// One K64 step for a 64x32 wave tile: 24 ds_read_b128 -> 48 MFMA between
// barriers (R8: 12/12 -> per-step fixed costs amortize 2x).
__device__ __forceinline__ void compute_tile(const char* buf, int rA0, int rB, int half,
                                             f32x16& acc0, f32x16& acc1) {
    __builtin_amdgcn_s_setprio(1);
    #pragma unroll
    for (int kc = 0; kc < 4; ++kc) {
        const int s0 = 2 * kc + half;
        half8 ah0 = *(const half8*)(buf + AH_OFF + swz(rA0,      s0));
        half8 ah1 = *(const half8*)(buf + AH_OFF + swz(rA0 + 32, s0));
        half8 al0 = *(const half8*)(buf + AL_OFF + swz(rA0,      s0));
        half8 al1 = *(const half8*)(buf + AL_OFF + swz(rA0 + 32, s0));
        half8 bh  = *(const half8*)(buf + BH_OFF + swz(rB, s0));
        half8 bl  = *(const half8*)(buf + BL_OFF + swz(rB, s0));
        acc0 = MFMA16(ah0, bh, acc0, 0, 0, 0);
        acc1 = MFMA16(ah1, bh, acc1, 0, 0, 0);
        acc0 = MFMA16(ah0, bl, acc0, 0, 0, 0);
        acc1 = MFMA16(ah1, bl, acc1, 0, 0, 0);
        acc0 = MFMA16(al0, bh, acc0, 0, 0, 0);
        acc1 = MFMA16(al1, bh, acc1, 0, 0, 0);
    }
    __builtin_amdgcn_s_setprio(0);
}

// K1: energy = Q.K^T per batch via split-f16 MFMA (hh+hl+lh), fused argmax.
// R8 winner structure (512 thr, 1 block/CU, 128x128, 8 waves of 64x32) with
// BK=64: 36 lgkm-only barriers (R8: 144 full barriers).
__global__ __launch_bounds__(512, 1)
void energy_argmax_kernel(const float* __restrict__ q,    // rgb   [B][C][HW]
                          const float* __restrict__ kmat, // depth [B][C][HW]
                          unsigned long long* __restrict__ best) // [B][C]
{
    const int bid = blockIdx.x;
    const int nid = (bid & 7) * 32 + (bid >> 3);   // XCD-chunk (256%8==0: bijective)
    const int d0  = (nid & 3) * BN;
    const int c0  = ((nid >> 2) & 3) * BM;
    const int b   = nid >> 4;

    const int tid  = threadIdx.x;
    const int lane = tid & 63;
    const int w    = tid >> 6;         // 0..7
    const int wm   = w >> 2;           // wave row (0,1): 64 rows each
    const int wn   = w & 3;            // wave col (0..3): 32 cols each

    __shared__ __align__(16) char sm[2 * BUF_SZ];
    char* buf0 = sm;
    char* buf1 = sm + BUF_SZ;

    const float* qb = q    + (size_t)b * CH * HW;
    const float* kb = kmat + (size_t)b * CH * HW;

    const int row = tid >> 2, sq = tid & 3;        // staging: 4 thr/row
    const float* aG = qb + (size_t)(c0 + row) * HW + sq * 16;
    const float* bG = kb + (size_t)(d0 + row) * HW + sq * 16;

    float4 av0[4], bv0[4], av1[4], bv1[4];

    // ---- prologue: tile0 -> buf0 ; tile1 loads in flight ----
    load_tile(aG, bG, 0, av0, bv0);
    stage_tile(buf0, av0, bv0, row, sq);
    load_tile(aG, bG, BK, av1, bv1);
    LGKM_BARRIER();

    f32x16 acc0 = {}, acc1 = {};

    const int rA0  = wm * 64 + (lane & 31);
    const int rB   = wn * 32 + (lane & 31);
    const int half = lane >> 5;                    // K8 half within each K16

    // body: {issue loads t+2 ; stage t+1 (writes hide under MFMA) ; compute t}
    for (int kt = 0; kt < NKT - 1; kt += 2) {
        // phase A: tiles -> even set holds t, odd set holds t+1
        if (kt + 2 < NKT) load_tile(aG, bG, (kt + 2) * BK, av0, bv0);
        stage_tile(buf1, av1, bv1, row, sq);
        compute_tile(buf0, rA0, rB, half, acc0, acc1);
        LGKM_BARRIER();
        // phase B
        if (kt + 3 < NKT) load_tile(aG, bG, (kt + 3) * BK, av1, bv1);
        if (kt + 2 < NKT) stage_tile(buf0, av0, bv0, row, sq);
        compute_tile(buf1, rA0, rB, half, acc0, acc1);
        LGKM_BARRIER();
    }
    // NKT=36 even: loop covers t=0..35 fully (stage of t+1 guarded by loads)

    // ---- epilogue: per-row argmax over this wave's 64x32 tile ----
    // C/D map (m74/m101): col = lane&31, row = (reg&3) + 8*(reg>>2) + 4*(lane>>5)
    const uint32_t didx = ~(uint32_t)(d0 + wn * 32 + (lane & 31));  // ties -> smallest d
    #pragma unroll
    for (int mi = 0; mi < 2; ++mi) {
        #pragma unroll
        for (int qr = 0; qr < 16; ++qr) {
            float v = (mi == 0) ? acc0[qr] : acc1[qr];
            int rowl = wm * 64 + mi * 32 + (qr & 3) + 8 * (qr >> 2) + 4 * (lane >> 5);
            unsigned long long p =
                ((unsigned long long)f32_sortable(v) << 32) | didx;
            #pragma unroll
            for (int off = 1; off < 32; off <<= 1) {   // reduce 32 cols (stays in half)
                unsigned long long o = __shfl_xor(p, off, 64);
                if (o > p) p = o;
            }
            if ((lane & 31) == 0)
                atomicMax(&best[(size_t)b * CH + c0 + rowl], p);
        }
    }
}

// K2: out[b][c][:] = rgb[b][c][:] + depth[b][argmax][:]
__global__ __launch_bounds__(256)
void gather_add_kernel(const float* __restrict__ rgb,
                       const float* __restrict__ depth,
                       const unsigned long long* __restrict__ best,
                       float* __restrict__ out)
{
    const int row = blockIdx.x;          // b*CH + c
    const int b   = row >> 9;            // /512
    const uint32_t idx = ~(uint32_t)(best[row] & 0xFFFFFFFFull);
    const float4* src = (const float4*)(rgb   + (size_t)row * HW);
    const float4* dep = (const float4*)(depth + ((size_t)b * CH + idx) * HW);
    float4*       dst = (float4*)(out + (size_t)row * HW);
    for (int j = threadIdx.x; j < HW / 4; j += 256) {
        float4 a = src[j], d = dep[j];
        float4 r; r.x = a.x + d.x; r.y = a.y + d.y; r.z = a.z + d.z; r.w = a.w + d.w;
        dst[j] = r;
    }
}

extern "C" void kernel_launch(void* const* d_in, const int* in_sizes, int n_in,
                              void* d_out, int out_size, void* d_ws, size_t ws_size,
                              hipStream_t stream)
{
    const float* rgb   = (const float*)d_in[0];
    const float* depth = (const float*)d_in[1];
    float* out = (float*)d_out;
    unsigned long long* best = (unsigned long long*)d_ws;  // 16*512*8 = 64 KB

    hipMemsetAsync(best, 0, (size_t)BATCH * CH * sizeof(unsigned long long), stream);

    energy_argmax_kernel<<<256, 512, 0, stream>>>(rgb, depth, best);

    gather_add_kernel<<<BATCH * CH, 256, 0, stream>>>(rgb, depth, best, out);
}